// Round 1
// baseline (49.483 us; speedup 1.0000x reference)
//
#include <hip/hip_runtime.h>

#define NBLK 2048
#define NTHR 256

__global__ __launch_bounds__(NTHR) void huber_partial(
    const float* __restrict__ x, const float* __restrict__ y,
    float* __restrict__ partial, long long n)
{
    const long long n4 = n >> 2;                 // float4 count
    const float4* __restrict__ x4 = (const float4*)x;
    const float4* __restrict__ y4 = (const float4*)y;

    long long tid = (long long)blockIdx.x * blockDim.x + threadIdx.x;
    long long stride = (long long)gridDim.x * blockDim.x;

    float acc = 0.0f;
    for (long long i = tid; i < n4; i += stride) {
        float4 a = x4[i];
        float4 b = y4[i];
        float d0 = a.x - b.x, d1 = a.y - b.y, d2 = a.z - b.z, d3 = a.w - b.w;
        float a0 = fabsf(d0), a1 = fabsf(d1), a2 = fabsf(d2), a3 = fabsf(d3);
        acc += (a0 <= 1.0f) ? 0.5f * d0 * d0 : a0;
        acc += (a1 <= 1.0f) ? 0.5f * d1 * d1 : a1;
        acc += (a2 <= 1.0f) ? 0.5f * d2 * d2 : a2;
        acc += (a3 <= 1.0f) ? 0.5f * d3 * d3 : a3;
    }

    // scalar tail (n not divisible by 4) — handled by thread 0 of block 0
    if (tid == 0) {
        for (long long i = n4 << 2; i < n; ++i) {
            float d = x[i] - y[i];
            float ad = fabsf(d);
            acc += (ad <= 1.0f) ? 0.5f * d * d : ad;
        }
    }

    // wave64 reduction
    #pragma unroll
    for (int off = 32; off > 0; off >>= 1)
        acc += __shfl_down(acc, off, 64);

    __shared__ float smem[NTHR / 64];
    int lane = threadIdx.x & 63;
    int wv   = threadIdx.x >> 6;
    if (lane == 0) smem[wv] = acc;
    __syncthreads();
    if (threadIdx.x == 0) {
        float t = 0.0f;
        #pragma unroll
        for (int i = 0; i < NTHR / 64; ++i) t += smem[i];
        partial[blockIdx.x] = t;
    }
}

__global__ __launch_bounds__(NTHR) void huber_final(
    const float* __restrict__ partial, float* __restrict__ out, float inv_n)
{
    float acc = 0.0f;
    for (int i = threadIdx.x; i < NBLK; i += NTHR)
        acc += partial[i];

    #pragma unroll
    for (int off = 32; off > 0; off >>= 1)
        acc += __shfl_down(acc, off, 64);

    __shared__ float smem[NTHR / 64];
    int lane = threadIdx.x & 63;
    int wv   = threadIdx.x >> 6;
    if (lane == 0) smem[wv] = acc;
    __syncthreads();
    if (threadIdx.x == 0) {
        float t = 0.0f;
        #pragma unroll
        for (int i = 0; i < NTHR / 64; ++i) t += smem[i];
        out[0] = t * inv_n;
    }
}

extern "C" void kernel_launch(void* const* d_in, const int* in_sizes, int n_in,
                              void* d_out, int out_size, void* d_ws, size_t ws_size,
                              hipStream_t stream)
{
    const float* x = (const float*)d_in[0];
    const float* y = (const float*)d_in[1];
    float* out = (float*)d_out;
    float* partial = (float*)d_ws;          // NBLK floats of scratch

    long long n = (long long)in_sizes[0];

    huber_partial<<<NBLK, NTHR, 0, stream>>>(x, y, partial, n);
    huber_final<<<1, NTHR, 0, stream>>>(partial, out, 1.0f / (double)n);
}